// Round 2
// baseline (1004.057 us; speedup 1.0000x reference)
//
#include <hip/hip_runtime.h>
#include <hip/hip_bf16.h>
#include <math.h>

// Problem constants
#define HDIM 128
#define NIN  384
#define CIN  512   // H + NIN
#define KNB  48
#define FFD  512
#define NNODES 8192

typedef __attribute__((ext_vector_type(8))) short bf16x8;
typedef __attribute__((ext_vector_type(4))) float f32x4;

__device__ __forceinline__ short f2b(float f) {
    union { unsigned int i; float f; } v; v.f = f;
    unsigned int u = v.i;
    unsigned int r = (u + 0x7FFFu + ((u >> 16) & 1u)) >> 16;
    return (short)(unsigned short)r;
}
__device__ __forceinline__ unsigned int pk2(float2 t) {
    return ((unsigned int)(unsigned short)f2b(t.y) << 16) |
           (unsigned int)(unsigned short)f2b(t.x);
}
__device__ __forceinline__ float gelu_exact(float x) {
    return 0.5f * x * (1.0f + erff(x * 0.7071067811865476f));
}

// ---------------------------------------------------------------------------
// Kernel 0: convert fp32 weights -> bf16, transposed (column-major) in ws.
// Layout (short offsets in ws):
//   W1T  [128 n][512 k] at 0      : W1T[n][k] = w1_w[k][n]
//   W2T  [128][128]     at 65536
//   W3T  [128][128]     at 81920
//   WinT [512 f][128 h] at 98304  : WinT[f][h] = fw_in_w[h][f]
//   WoutT[128 h][512 f] at 163840 : WoutT[h][f] = fw_out_w[f][h]
// ---------------------------------------------------------------------------
__global__ __launch_bounds__(256) void k_pack(
    const float* __restrict__ w1, const float* __restrict__ w2,
    const float* __restrict__ w3, const float* __restrict__ win,
    const float* __restrict__ wout, short* __restrict__ dst)
{
    int i = blockIdx.x * 256 + threadIdx.x;
    if (i >= 229376) return;
    float v;
    if (i < 65536)       { int n = i >> 9,  k = i & 511;                 v = w1[k*128 + n]; }
    else if (i < 81920)  { int j = i - 65536;  int n = j >> 7, k = j & 127; v = w2[k*128 + n]; }
    else if (i < 98304)  { int j = i - 81920;  int n = j >> 7, k = j & 127; v = w3[k*128 + n]; }
    else if (i < 163840) { int j = i - 98304;  int f = j >> 7, h = j & 127; v = win[h*512 + f]; }
    else                 { int j = i - 163840; int h = j >> 9, f = j & 511; v = wout[f*128 + h]; }
    dst[i] = f2b(v);
}

// ---------------------------------------------------------------------------
// Kernel 1: per-node message MLP + neighbor reduction.
// 1 node per block, 256 threads = 4 waves. M = 48 neighbor rows (3 M-tiles),
// N = 128 (each wave owns 32 cols). GEMM1 K=512 ([h_v | h_e] concat, h_v
// chunks broadcast to all 48 rows). mfma_f32_16x16x32_bf16, fp32 accumulate.
// fp32 global data is converted to bf16 (RNE) during LDS staging.
// LDS row strides: x/w = 40 shorts (80 B = 5*16), m = 136 shorts (272 B = 17*16).
// ---------------------------------------------------------------------------
__global__ __launch_bounds__(256) void k_msg(
    const float* __restrict__ h_v, const float* __restrict__ h_e,
    const float* __restrict__ mask_attend,
    const short* __restrict__ w1t, const short* __restrict__ w2t,
    const short* __restrict__ w3t,
    const float* __restrict__ b1, const float* __restrict__ b2,
    const float* __restrict__ b3,
    float* __restrict__ dh)
{
    __shared__ short x_lds[48 * 40];    // X chunk [48][32] bf16, padded
    __shared__ short w_lds[128 * 40];   // W chunk [128 n][32 k] bf16, padded
    __shared__ short m_lds[48 * 136];   // inter-layer activations [48][128]
    __shared__ float msk[48];

    const int tid  = threadIdx.x;
    const int wave = tid >> 6, lane = tid & 63;
    const int lr   = lane & 15, quad = lane >> 4;
    const int node = blockIdx.x;

    if (tid < 48) msk[tid] = mask_attend[node * 48 + tid] * (1.0f / 30.0f);

    const float2* hv2 = (const float2*)h_v;   // 64 float2 per node row
    const float2* he2 = (const float2*)h_e;   // 192 float2 per (node,neighbor)
    unsigned int* x32 = (unsigned int*)x_lds;

    f32x4 acc[3][2];
    for (int m = 0; m < 3; ++m)
        for (int nt = 0; nt < 2; ++nt) acc[m][nt] = {0.f, 0.f, 0.f, 0.f};

    // ---------------- GEMM1: K = 512 in 16 chunks of 32 ----------------
    for (int kc = 0; kc < 16; ++kc) {
        __syncthreads();  // protect x_lds/w_lds from previous chunk's readers
        // stage X chunk: 48 rows x 16 u32 (32 bf16) = 768 writes
        if (kc < 4) {
            for (int i = 0; i < 3; ++i) {
                int e = tid + i * 256; int row = e >> 4, c2 = e & 15;
                float2 t = hv2[node * 64 + kc * 16 + c2];
                x32[row * 20 + c2] = pk2(t);
            }
        } else {
            int kc2 = kc - 4;
            for (int i = 0; i < 3; ++i) {
                int e = tid + i * 256; int row = e >> 4, c2 = e & 15;
                float2 t = he2[(node * 48 + row) * 192 + kc2 * 16 + c2];
                x32[row * 20 + c2] = pk2(t);
            }
        }
        // stage W1T chunk (already bf16): 128 n-rows x 8 uint2 (32 bf16)
        {
            const uint2* wsrc = (const uint2*)w1t;
            uint2* wdst = (uint2*)w_lds;
            for (int i = 0; i < 4; ++i) {
                int q = tid + i * 256; int n = q >> 3, k4 = q & 7;
                wdst[n * 10 + k4] = wsrc[n * 128 + kc * 8 + k4];
            }
        }
        __syncthreads();
        bf16x8 af[3], bfr[2];
        for (int m = 0; m < 3; ++m)
            af[m] = *(const bf16x8*)&x_lds[(m * 16 + lr) * 40 + quad * 8];
        for (int nt = 0; nt < 2; ++nt)
            bfr[nt] = *(const bf16x8*)&w_lds[(wave * 32 + nt * 16 + lr) * 40 + quad * 8];
        for (int m = 0; m < 3; ++m)
            for (int nt = 0; nt < 2; ++nt)
                acc[m][nt] = __builtin_amdgcn_mfma_f32_16x16x32_bf16(af[m], bfr[nt], acc[m][nt], 0, 0, 0);
    }

    // epilogue 1: gelu(acc + b1) -> m_lds (bf16). m_lds untouched so far.
    for (int nt = 0; nt < 2; ++nt) {
        int col = wave * 32 + nt * 16 + lr;
        float bias = b1[col];
        for (int m = 0; m < 3; ++m)
            for (int j = 0; j < 4; ++j) {
                int row = m * 16 + quad * 4 + j;
                m_lds[row * 136 + col] = f2b(gelu_exact(acc[m][nt][j] + bias));
            }
    }

    // ---------------- GEMM2 (w2, gelu) and GEMM3 (w3, mask+reduce) ------
    for (int layer = 0; layer < 2; ++layer) {
        const short* wt = layer ? w3t : w2t;
        for (int m = 0; m < 3; ++m)
            for (int nt = 0; nt < 2; ++nt) acc[m][nt] = {0.f, 0.f, 0.f, 0.f};

        for (int kc = 0; kc < 4; ++kc) {
            __syncthreads();   // also makes epilogue m_lds writes visible (kc=0)
            const uint2* wsrc = (const uint2*)wt;
            uint2* wdst = (uint2*)w_lds;
            for (int i = 0; i < 4; ++i) {
                int q = tid + i * 256; int n = q >> 3, k4 = q & 7;
                wdst[n * 10 + k4] = wsrc[n * 32 + kc * 8 + k4];
            }
            __syncthreads();
            bf16x8 af[3], bfr[2];
            for (int m = 0; m < 3; ++m)
                af[m] = *(const bf16x8*)&m_lds[(m * 16 + lr) * 136 + kc * 32 + quad * 8];
            for (int nt = 0; nt < 2; ++nt)
                bfr[nt] = *(const bf16x8*)&w_lds[(wave * 32 + nt * 16 + lr) * 40 + quad * 8];
            for (int m = 0; m < 3; ++m)
                for (int nt = 0; nt < 2; ++nt)
                    acc[m][nt] = __builtin_amdgcn_mfma_f32_16x16x32_bf16(af[m], bfr[nt], acc[m][nt], 0, 0, 0);
        }
        __syncthreads();  // all reads of m_lds complete before overwrite

        if (layer == 0) {
            for (int nt = 0; nt < 2; ++nt) {
                int col = wave * 32 + nt * 16 + lr;
                float bias = b2[col];
                for (int m = 0; m < 3; ++m)
                    for (int j = 0; j < 4; ++j) {
                        int row = m * 16 + quad * 4 + j;
                        m_lds[row * 136 + col] = f2b(gelu_exact(acc[m][nt][j] + bias));
                    }
            }
        } else {
            // bias + mask(/30) + column-sum over 48 neighbor rows -> dh (fp32)
            for (int nt = 0; nt < 2; ++nt) {
                int col = wave * 32 + nt * 16 + lr;
                float bias = b3[col];
                float s = 0.f;
                for (int m = 0; m < 3; ++m)
                    for (int j = 0; j < 4; ++j) {
                        int row = m * 16 + quad * 4 + j;
                        s += (acc[m][nt][j] + bias) * msk[row];
                    }
                s += __shfl_xor(s, 16);   // sum across quad bit 0
                s += __shfl_xor(s, 32);   // sum across quad bit 1
                if (quad == nt)           // quad0 -> ntile0, quad1 -> ntile1
                    dh[node * 128 + col] = s;
            }
        }
    }
}

// ---------------------------------------------------------------------------
// Kernel 2: LN1 + FFN (128->512 gelu ->128) + LN2 + mask_v. 16 nodes/block.
// B-fragments read directly from the L2-resident packed bf16 weights.
// ---------------------------------------------------------------------------
__global__ __launch_bounds__(256) void k_ffn(
    const float* __restrict__ h_v, const float* __restrict__ dh,
    const float* __restrict__ mask_v,
    const float* __restrict__ ln1g, const float* __restrict__ ln1b,
    const float* __restrict__ ln2g, const float* __restrict__ ln2b,
    const short* __restrict__ wint, const short* __restrict__ woutt,
    const float* __restrict__ fwinb, const float* __restrict__ fwoutb,
    float* __restrict__ out)
{
    __shared__ float h1f[16 * 128];   // LN1 output fp32 (residual)
    __shared__ short h1b[16 * 136];   // LN1 output bf16 (GEMM A operand)
    __shared__ short a1[16 * 520];    // gelu(h@Win+b) bf16
    __shared__ float u2l[16 * 132];   // pre-LN2 fp32

    const int tid  = threadIdx.x;
    const int wave = tid >> 6, lane = tid & 63;
    const int lr   = lane & 15, quad = lane >> 4;
    const int nb   = blockIdx.x * 16;

    // phase 0: u = h_v + dh ; LN1
    {
        int row = tid >> 4, cg = tid & 15;
        int gbase = (nb + row) * 128 + cg * 8;
        const float4* hv4 = (const float4*)(h_v + gbase);
        const float4* dp4 = (const float4*)(dh + gbase);
        float u[8];
        float4 a0 = hv4[0], a1v = hv4[1], d0 = dp4[0], d1 = dp4[1];
        u[0]=a0.x+d0.x; u[1]=a0.y+d0.y; u[2]=a0.z+d0.z; u[3]=a0.w+d0.w;
        u[4]=a1v.x+d1.x; u[5]=a1v.y+d1.y; u[6]=a1v.z+d1.z; u[7]=a1v.w+d1.w;
        float s1 = 0.f, s2 = 0.f;
        for (int i = 0; i < 8; ++i) { s1 += u[i]; s2 += u[i] * u[i]; }
        for (int m = 1; m < 16; m <<= 1) { s1 += __shfl_xor(s1, m); s2 += __shfl_xor(s2, m); }
        float mu = s1 * (1.f / 128.f);
        float var = s2 * (1.f / 128.f) - mu * mu;
        float rs = rsqrtf(var + 1e-5f);
        for (int i = 0; i < 8; ++i) {
            int c = cg * 8 + i;
            float h = (u[i] - mu) * rs * ln1g[c] + ln1b[c];
            h1f[row * 128 + c] = h;
            h1b[row * 136 + c] = f2b(h);
        }
    }
    __syncthreads();

    // GEMM A: [16 x 128] @ WinT -> [16 x 512]; each wave owns 128 f-cols
    f32x4 acc8[8];
    for (int nt = 0; nt < 8; ++nt) acc8[nt] = {0.f, 0.f, 0.f, 0.f};
    for (int kc = 0; kc < 4; ++kc) {
        bf16x8 af = *(const bf16x8*)&h1b[lr * 136 + kc * 32 + quad * 8];
        for (int nt = 0; nt < 8; ++nt) {
            int f = wave * 128 + nt * 16 + lr;
            bf16x8 bfr = *(const bf16x8*)&wint[f * 128 + kc * 32 + quad * 8];
            acc8[nt] = __builtin_amdgcn_mfma_f32_16x16x32_bf16(af, bfr, acc8[nt], 0, 0, 0);
        }
    }
    for (int nt = 0; nt < 8; ++nt) {
        int f = wave * 128 + nt * 16 + lr;
        float bias = fwinb[f];
        for (int j = 0; j < 4; ++j) {
            int row = quad * 4 + j;
            a1[row * 520 + f] = f2b(gelu_exact(acc8[nt][j] + bias));
        }
    }
    __syncthreads();

    // GEMM B: [16 x 512] @ WoutT -> [16 x 128]; each wave owns 32 h-cols
    f32x4 acc2[2];
    for (int nt = 0; nt < 2; ++nt) acc2[nt] = {0.f, 0.f, 0.f, 0.f};
    for (int kc = 0; kc < 16; ++kc) {
        bf16x8 af = *(const bf16x8*)&a1[lr * 520 + kc * 32 + quad * 8];
        for (int nt = 0; nt < 2; ++nt) {
            int h = wave * 32 + nt * 16 + lr;
            bf16x8 bfr = *(const bf16x8*)&woutt[h * 512 + kc * 32 + quad * 8];
            acc2[nt] = __builtin_amdgcn_mfma_f32_16x16x32_bf16(af, bfr, acc2[nt], 0, 0, 0);
        }
    }
    for (int nt = 0; nt < 2; ++nt) {
        int h = wave * 32 + nt * 16 + lr;
        float bias = fwoutb[h];
        for (int j = 0; j < 4; ++j) {
            int row = quad * 4 + j;
            u2l[row * 132 + h] = h1f[row * 128 + h] + acc2[nt][j] + bias;
        }
    }
    __syncthreads();

    // phase 3: LN2 + mask_v + float4 stores
    {
        int row = tid >> 4, cg = tid & 15;
        float u[8];
        for (int i = 0; i < 8; ++i) u[i] = u2l[row * 132 + cg * 8 + i];
        float s1 = 0.f, s2 = 0.f;
        for (int i = 0; i < 8; ++i) { s1 += u[i]; s2 += u[i] * u[i]; }
        for (int m = 1; m < 16; m <<= 1) { s1 += __shfl_xor(s1, m); s2 += __shfl_xor(s2, m); }
        float mu = s1 * (1.f / 128.f);
        float var = s2 * (1.f / 128.f) - mu * mu;
        float rs = rsqrtf(var + 1e-5f);
        float mv = mask_v[nb + row];
        float o[8];
        for (int i = 0; i < 8; ++i) {
            int c = cg * 8 + i;
            o[i] = ((u[i] - mu) * rs * ln2g[c] + ln2b[c]) * mv;
        }
        float* op = out + (nb + row) * 128 + cg * 8;
        ((float4*)op)[0] = make_float4(o[0], o[1], o[2], o[3]);
        ((float4*)op)[1] = make_float4(o[4], o[5], o[6], o[7]);
    }
}

extern "C" void kernel_launch(void* const* d_in, const int* in_sizes, int n_in,
                              void* d_out, int out_size, void* d_ws, size_t ws_size,
                              hipStream_t stream) {
    const float* h_v         = (const float*)d_in[0];
    const float* h_e         = (const float*)d_in[1];
    const float* mask_v      = (const float*)d_in[2];
    const float* mask_attend = (const float*)d_in[3];
    const float* w1_w        = (const float*)d_in[4];
    const float* w1_b        = (const float*)d_in[5];
    const float* w2_w        = (const float*)d_in[6];
    const float* w2_b        = (const float*)d_in[7];
    const float* w3_w        = (const float*)d_in[8];
    const float* w3_b        = (const float*)d_in[9];
    const float* ln1g        = (const float*)d_in[10];
    const float* ln1b        = (const float*)d_in[11];
    const float* ln2g        = (const float*)d_in[12];
    const float* ln2b        = (const float*)d_in[13];
    const float* fw_in_w     = (const float*)d_in[14];
    const float* fw_in_b     = (const float*)d_in[15];
    const float* fw_out_w    = (const float*)d_in[16];
    const float* fw_out_b    = (const float*)d_in[17];

    short* pk    = (short*)d_ws;
    short* w1t   = pk;
    short* w2t   = pk + 65536;
    short* w3t   = pk + 81920;
    short* wint  = pk + 98304;
    short* woutt = pk + 163840;
    float* dh    = (float*)((char*)d_ws + 458752);  // 8192*128 fp32 = 4 MB

    k_pack<<<896, 256, 0, stream>>>(w1_w, w2_w, w3_w, fw_in_w, fw_out_w, pk);
    k_msg<<<NNODES, 256, 0, stream>>>(h_v, h_e, mask_attend, w1t, w2t, w3t,
                                      w1_b, w2_b, w3_b, dh);
    k_ffn<<<NNODES / 16, 256, 0, stream>>>(h_v, dh, mask_v, ln1g, ln1b, ln2g, ln2b,
                                           wint, woutt, fw_in_b, fw_out_b,
                                           (float*)d_out);
}